// Round 1
// baseline (126.550 us; speedup 1.0000x reference)
//
#include <hip/hip_runtime.h>

typedef __attribute__((ext_vector_type(8))) short bf16x8;
typedef __attribute__((ext_vector_type(4))) float f32x4;

#define S_  2048
#define D_  1024
#define H_  16
#define DK_ 64
#define DV_ 64

__device__ __forceinline__ unsigned short f2bf(float x) {
    union { float f; unsigned u; } v; v.f = x;
    unsigned r = v.u + 0x7fffu + ((v.u >> 16) & 1u);
    return (unsigned short)(r >> 16);
}

__device__ __forceinline__ void gload16(const unsigned short* g, unsigned short* l) {
    __builtin_amdgcn_global_load_lds((const __attribute__((address_space(1))) void*)g,
                                     (__attribute__((address_space(3))) void*)l, 16, 0, 0);
}

// ---------------- convert f32 -> bf16 (vectorized) ----------------
__global__ __launch_bounds__(256) void cvt_f32_bf16(const float* __restrict__ in,
                                                    unsigned short* __restrict__ out, int n4) {
    int i = blockIdx.x * 256 + threadIdx.x;
    if (i >= n4) return;
    float4 v = ((const float4*)in)[i];
    ushort4 o;
    o.x = f2bf(v.x); o.y = f2bf(v.y); o.z = f2bf(v.z); o.w = f2bf(v.w);
    ((ushort4*)out)[i] = o;
}

// ---------------- tiled transpose f32 -> bf16: out[c][r] = in[r][c] ----------------
__global__ void transpose_w(const float* __restrict__ in, unsigned short* __restrict__ out,
                            int R, int C, long ibs, long obs) {
    __shared__ float t[32][33];
    const float* I = in + (long)blockIdx.z * ibs;
    unsigned short* O = out + (long)blockIdx.z * obs;
    int c0 = blockIdx.x * 32, r0 = blockIdx.y * 32;
    t[threadIdx.y][threadIdx.x] = I[(long)(r0 + threadIdx.y) * C + c0 + threadIdx.x];
    __syncthreads();
    O[(long)(c0 + threadIdx.y) * R + r0 + threadIdx.x] = f2bf(t[threadIdx.x][threadIdx.y]);
}

// ---------------- 128x64-tile bf16 MFMA GEMM body ----------------
// C[m][n] = sum_k A[m][k] * Bt[n][k], A: [M][1024] bf16, Bt: [64][1024] bf16 (row n contiguous k)
// MODE 0: bf16 store C[gm*ldc+gn]; MODE 1: bf16 transposed store C[gn*ldc+gm]; MODE 2: f32 store
template<int MODE>
__device__ __forceinline__ void gemm128x64(unsigned short* As, unsigned short* Bs,
                                           const unsigned short* __restrict__ A,
                                           const unsigned short* __restrict__ Bt,
                                           void* __restrict__ C, int m0, int ldc) {
    const int tid = threadIdx.x, wv = tid >> 6, lane = tid & 63, lg = lane >> 4, lr = lane & 15;
    const int wm = wv & 1, wn = wv >> 1;
    f32x4 acc[4][2] = {};
    const unsigned short* Ab = A + (size_t)m0 * D_;
    for (int kt = 0; kt < 16; ++kt) {
        __syncthreads();
        // stage A tile [128][64] : 1024 16B-chunks, swizzled source, linear LDS dest
        #pragma unroll
        for (int it = 0; it < 4; ++it) {
            int c = it * 256 + wv * 64 + lane;
            int row = c >> 3, jj = (c & 7) ^ (row & 7);
            gload16(Ab + kt * 64 + row * D_ + jj * 8, &As[(it * 256 + wv * 64) * 8]);
        }
        // stage Bt tile [64][64]
        #pragma unroll
        for (int it = 0; it < 2; ++it) {
            int c = it * 256 + wv * 64 + lane;
            int row = c >> 3, jj = (c & 7) ^ (row & 7);
            gload16(Bt + kt * 64 + row * D_ + jj * 8, &Bs[(it * 256 + wv * 64) * 8]);
        }
        __syncthreads();
        #pragma unroll
        for (int kk = 0; kk < 2; ++kk) {
            bf16x8 af[4], bfr[2];
            #pragma unroll
            for (int mf = 0; mf < 4; ++mf) {
                int r = wm * 64 + mf * 16 + lr;
                af[mf] = *(const bf16x8*)&As[(r * 8 + ((kk * 4 + lg) ^ (r & 7))) * 8];
            }
            #pragma unroll
            for (int nf = 0; nf < 2; ++nf) {
                int r = wn * 32 + nf * 16 + lr;
                bfr[nf] = *(const bf16x8*)&Bs[(r * 8 + ((kk * 4 + lg) ^ (r & 7))) * 8];
            }
            #pragma unroll
            for (int mf = 0; mf < 4; ++mf)
                #pragma unroll
                for (int nf = 0; nf < 2; ++nf)
                    acc[mf][nf] = __builtin_amdgcn_mfma_f32_16x16x32_bf16(af[mf], bfr[nf], acc[mf][nf], 0, 0, 0);
        }
    }
    #pragma unroll
    for (int mf = 0; mf < 4; ++mf)
        #pragma unroll
        for (int nf = 0; nf < 2; ++nf)
            #pragma unroll
            for (int j = 0; j < 4; ++j) {
                int gm = m0 + wm * 64 + mf * 16 + lg * 4 + j;
                int gn = wn * 32 + nf * 16 + lr;
                float v = acc[mf][nf][j];
                if (MODE == 0)      ((unsigned short*)C)[(size_t)gm * ldc + gn] = f2bf(v);
                else if (MODE == 1) ((unsigned short*)C)[(size_t)gn * ldc + gm] = f2bf(v);
                else                ((float*)C)[(size_t)gm * ldc + gn] = v;
            }
}

// ---------------- QKV projection kernel ----------------
__global__ __launch_bounds__(256, 2) void proj_kernel(
    const unsigned short* __restrict__ Eq, const unsigned short* __restrict__ Ek,
    const unsigned short* __restrict__ Ev, const unsigned short* __restrict__ Wqt,
    const unsigned short* __restrict__ Wkt, const unsigned short* __restrict__ Wvt,
    unsigned short* __restrict__ Qb, unsigned short* __restrict__ Kb,
    unsigned short* __restrict__ Vtb) {
    __shared__ unsigned short As[128 * 64];
    __shared__ unsigned short Bs[64 * 64];
    int z = blockIdx.z, which = z >> 4, h = z & 15;
    int m0 = blockIdx.x * 128;
    const unsigned short* A  = which == 0 ? Eq : which == 1 ? Ek : Ev;
    const unsigned short* Bt = (which == 0 ? Wqt : which == 1 ? Wkt : Wvt) + (size_t)h * DK_ * D_;
    if (which == 2)
        gemm128x64<1>(As, Bs, A, Bt, Vtb + (size_t)h * DV_ * S_, m0, S_);
    else
        gemm128x64<0>(As, Bs, A, Bt, (which ? Kb : Qb) + (size_t)h * S_ * DK_, m0, DK_);
}

// ---------------- output projection kernel ----------------
__global__ __launch_bounds__(256, 2) void out_gemm(const unsigned short* __restrict__ Cat,
                                                   const unsigned short* __restrict__ Wot,
                                                   float* __restrict__ Out) {
    __shared__ unsigned short As[128 * 64];
    __shared__ unsigned short Bs[64 * 64];
    int m0 = blockIdx.x * 128, n0 = blockIdx.y * 64;
    gemm128x64<2>(As, Bs, Cat, Wot + (size_t)n0 * D_, Out + n0, m0, D_);
}

// ---------------- flash attention kernel ----------------
// grid (S/64, H), 256 threads (4 waves); wave w owns q rows [s0+16w, s0+16w+16)
__global__ __launch_bounds__(256, 2) void attn_kernel(
    const unsigned short* __restrict__ Qb, const unsigned short* __restrict__ Kb,
    const unsigned short* __restrict__ Vtb, unsigned short* __restrict__ Cat) {
    __shared__ unsigned short Ks[64 * 64];
    __shared__ unsigned short Vs[64 * 64];
    __shared__ unsigned short Ps[4][16 * 64];

    const int h = blockIdx.y;
    const int s0 = blockIdx.x * 64;
    const int tid = threadIdx.x, wv = tid >> 6, lane = tid & 63, lg = lane >> 4, lr = lane & 15;

    const unsigned short* Qh = Qb + (size_t)h * S_ * DK_;
    bf16x8 qf0, qf1;
    {
        const unsigned short* qrow = Qh + (size_t)(s0 + wv * 16 + lr) * DK_;
        qf0 = *(const bf16x8*)(qrow + lg * 8);
        qf1 = *(const bf16x8*)(qrow + 32 + lg * 8);
    }
    float m_run[4], l_run[4];
    f32x4 o_acc[4] = {};
    #pragma unroll
    for (int j = 0; j < 4; ++j) { m_run[j] = -1e30f; l_run[j] = 0.f; }

    const unsigned short* Kh = Kb + (size_t)h * S_ * DK_;
    const unsigned short* Vh = Vtb + (size_t)h * DV_ * S_;
    unsigned short* Pw = &Ps[wv][0];

    for (int t = 0; t < S_ / 64; ++t) {
        __syncthreads();
        const unsigned short* Ksrc = Kh + t * 64 * DK_;
        #pragma unroll
        for (int it = 0; it < 2; ++it) {
            int c = it * 256 + wv * 64 + lane;
            int row = c >> 3, jj = (c & 7) ^ (row & 7);
            gload16(Ksrc + row * DK_ + jj * 8, &Ks[(it * 256 + wv * 64) * 8]);
        }
        const unsigned short* Vsrc = Vh + t * 64;
        #pragma unroll
        for (int it = 0; it < 2; ++it) {
            int c = it * 256 + wv * 64 + lane;
            int row = c >> 3, jj = (c & 7) ^ (row & 7);
            gload16(Vsrc + row * S_ + jj * 8, &Vs[(it * 256 + wv * 64) * 8]);
        }
        __syncthreads();

        // scores S[q=16][key=64] per wave: C layout row=lg*4+j, col=n*16+lr
        f32x4 sc[4] = {};
        #pragma unroll
        for (int kk = 0; kk < 2; ++kk) {
            bf16x8 q = kk ? qf1 : qf0;
            #pragma unroll
            for (int n = 0; n < 4; ++n) {
                int r = n * 16 + lr;
                bf16x8 kf = *(const bf16x8*)&Ks[(r * 8 + ((kk * 4 + lg) ^ (r & 7))) * 8];
                sc[n] = __builtin_amdgcn_mfma_f32_16x16x32_bf16(q, kf, sc[n], 0, 0, 0);
            }
        }
        #pragma unroll
        for (int n = 0; n < 4; ++n) sc[n] *= 0.125f;

        float alpha[4], rs[4];
        #pragma unroll
        for (int j = 0; j < 4; ++j) {
            float v = fmaxf(fmaxf(sc[0][j], sc[1][j]), fmaxf(sc[2][j], sc[3][j]));
            v = fmaxf(v, __shfl_xor(v, 1)); v = fmaxf(v, __shfl_xor(v, 2));
            v = fmaxf(v, __shfl_xor(v, 4)); v = fmaxf(v, __shfl_xor(v, 8));
            float mn = fmaxf(m_run[j], v);
            alpha[j] = __expf(m_run[j] - mn);
            m_run[j] = mn;
            rs[j] = 0.f;
        }
        #pragma unroll
        for (int n = 0; n < 4; ++n)
            #pragma unroll
            for (int j = 0; j < 4; ++j) {
                float p = __expf(sc[n][j] - m_run[j]);
                sc[n][j] = p;
                rs[j] += p;
            }
        #pragma unroll
        for (int j = 0; j < 4; ++j) {
            float v = rs[j];
            v += __shfl_xor(v, 1); v += __shfl_xor(v, 2);
            v += __shfl_xor(v, 4); v += __shfl_xor(v, 8);
            l_run[j] = l_run[j] * alpha[j] + v;
        }
        #pragma unroll
        for (int n = 0; n < 4; ++n) {
            f32x4 o = o_acc[n];
            o[0] *= alpha[0]; o[1] *= alpha[1]; o[2] *= alpha[2]; o[3] *= alpha[3];
            o_acc[n] = o;
        }
        // redistribute P to A-fragment layout through per-wave swizzled LDS
        #pragma unroll
        for (int n = 0; n < 4; ++n)
            #pragma unroll
            for (int j = 0; j < 4; ++j) {
                int row = lg * 4 + j, col = n * 16 + lr;
                int chunk = (col >> 3) ^ (row & 7);
                Pw[(row * 8 + chunk) * 8 + (col & 7)] = f2bf(sc[n][j]);
            }
        asm volatile("s_waitcnt lgkmcnt(0)" ::: "memory");
        bf16x8 pf[2];
        #pragma unroll
        for (int kk = 0; kk < 2; ++kk)
            pf[kk] = *(const bf16x8*)&Pw[(lr * 8 + ((kk * 4 + lg) ^ (lr & 7))) * 8];
        #pragma unroll
        for (int n = 0; n < 4; ++n)
            #pragma unroll
            for (int kk = 0; kk < 2; ++kk) {
                int r = n * 16 + lr;
                bf16x8 vf = *(const bf16x8*)&Vs[(r * 8 + ((kk * 4 + lg) ^ (r & 7))) * 8];
                o_acc[n] = __builtin_amdgcn_mfma_f32_16x16x32_bf16(pf[kk], vf, o_acc[n], 0, 0, 0);
            }
    }
    float inv_l[4];
    #pragma unroll
    for (int j = 0; j < 4; ++j) inv_l[j] = 1.f / l_run[j];
    #pragma unroll
    for (int n = 0; n < 4; ++n)
        #pragma unroll
        for (int j = 0; j < 4; ++j) {
            int s = s0 + wv * 16 + lg * 4 + j;
            Cat[(size_t)s * (H_ * DV_) + h * DV_ + n * 16 + lr] = f2bf(o_acc[n][j] * inv_l[j]);
        }
}

extern "C" void kernel_launch(void* const* d_in, const int* in_sizes, int n_in,
                              void* d_out, int out_size, void* d_ws, size_t ws_size,
                              hipStream_t stream) {
    const float* enc_q = (const float*)d_in[0];
    const float* enc_k = (const float*)d_in[1];
    const float* enc_v = (const float*)d_in[2];
    const float* W_q   = (const float*)d_in[3];
    const float* W_k   = (const float*)d_in[4];
    const float* W_v   = (const float*)d_in[5];
    const float* W_out = (const float*)d_in[6];
    float* out = (float*)d_out;

    unsigned short* Eqb = (unsigned short*)d_ws;       // [S][D] bf16
    unsigned short* Ekb = Eqb + 2048 * 1024;
    unsigned short* Evb = Ekb + 2048 * 1024;
    unsigned short* Wqt = Evb + 2048 * 1024;           // [H][DK][D] bf16
    unsigned short* Wkt = Wqt + 1024 * 1024;
    unsigned short* Wvt = Wkt + 1024 * 1024;
    unsigned short* Wot = Wvt + 1024 * 1024;           // [D][H*DV] transposed bf16
    unsigned short* Qb  = Wot + 1024 * 1024;           // [H][S][DK] bf16
    unsigned short* Kb  = Qb  + 2048 * 1024;           // [H][S][DK]
    unsigned short* Vtb = Kb  + 2048 * 1024;           // [H][DV][S]
    unsigned short* Cat = Vtb + 2048 * 1024;           // [S][H*DV]

    cvt_f32_bf16<<<2048, 256, 0, stream>>>(enc_q, Eqb, 524288);
    cvt_f32_bf16<<<2048, 256, 0, stream>>>(enc_k, Ekb, 524288);
    cvt_f32_bf16<<<2048, 256, 0, stream>>>(enc_v, Evb, 524288);
    dim3 tb(32, 32);
    transpose_w<<<dim3(2, 32, 16), tb, 0, stream>>>(W_q, Wqt, 1024, 64, 65536, 65536);
    transpose_w<<<dim3(2, 32, 16), tb, 0, stream>>>(W_k, Wkt, 1024, 64, 65536, 65536);
    transpose_w<<<dim3(2, 32, 16), tb, 0, stream>>>(W_v, Wvt, 1024, 64, 65536, 65536);
    transpose_w<<<dim3(32, 32, 1), tb, 0, stream>>>(W_out, Wot, 1024, 1024, 0, 0);
    proj_kernel<<<dim3(16, 1, 48), 256, 0, stream>>>(Eqb, Ekb, Evb, Wqt, Wkt, Wvt, Qb, Kb, Vtb);
    attn_kernel<<<dim3(32, 16), 256, 0, stream>>>(Qb, Kb, Vtb, Cat);
    out_gemm<<<dim3(16, 16), 256, 0, stream>>>(Cat, Wot, out);
}

// Round 2
// 106.176 us; speedup vs baseline: 1.1919x; 1.1919x over previous
//
#include <hip/hip_runtime.h>

typedef __attribute__((ext_vector_type(8))) short bf16x8;
typedef __attribute__((ext_vector_type(4))) float f32x4;
typedef __attribute__((ext_vector_type(4))) short s16x4;

#define S_  2048
#define D_  1024
#define H_  16
#define DK_ 64
#define DV_ 64

__device__ __forceinline__ unsigned short f2bf(float x) {
    union { float f; unsigned u; } v; v.f = x;
    unsigned r = v.u + 0x7fffu + ((v.u >> 16) & 1u);
    return (unsigned short)(r >> 16);
}

__device__ __forceinline__ void gload16(const unsigned short* g, unsigned short* l) {
    __builtin_amdgcn_global_load_lds((const __attribute__((address_space(1))) void*)g,
                                     (__attribute__((address_space(3))) void*)l, 16, 0, 0);
}

// ---------------- convert f32 -> bf16, 3 tensors fused ----------------
__global__ __launch_bounds__(256) void cvt_f32_bf16(const float* __restrict__ i0,
                                                    const float* __restrict__ i1,
                                                    const float* __restrict__ i2,
                                                    unsigned short* __restrict__ o0,
                                                    unsigned short* __restrict__ o1,
                                                    unsigned short* __restrict__ o2, int n4) {
    int i = blockIdx.x * 256 + threadIdx.x;
    if (i >= n4) return;
    const float* in = blockIdx.y == 0 ? i0 : blockIdx.y == 1 ? i1 : i2;
    unsigned short* out = blockIdx.y == 0 ? o0 : blockIdx.y == 1 ? o1 : o2;
    float4 v = ((const float4*)in)[i];
    ushort4 o;
    o.x = f2bf(v.x); o.y = f2bf(v.y); o.z = f2bf(v.z); o.w = f2bf(v.w);
    ((ushort4*)out)[i] = o;
}

// ---------------- per-head weight transpose f32 -> bf16 ----------------
// z = which*16 + h ; in [1024][64] per head -> out [64][1024]
__global__ void transpose_qkv(const float* __restrict__ Wq, const float* __restrict__ Wk,
                              const float* __restrict__ Wv, unsigned short* __restrict__ Oq,
                              unsigned short* __restrict__ Ok, unsigned short* __restrict__ Ov) {
    __shared__ float t[32][33];
    int which = blockIdx.z >> 4, h = blockIdx.z & 15;
    const float* I = (which == 0 ? Wq : which == 1 ? Wk : Wv) + (long)h * 65536;
    unsigned short* O = (which == 0 ? Oq : which == 1 ? Ok : Ov) + (long)h * 65536;
    int c0 = blockIdx.x * 32, r0 = blockIdx.y * 32;
    t[threadIdx.y][threadIdx.x] = I[(long)(r0 + threadIdx.y) * 64 + c0 + threadIdx.x];
    __syncthreads();
    O[(long)(c0 + threadIdx.y) * 1024 + r0 + threadIdx.x] = f2bf(t[threadIdx.x][threadIdx.y]);
}

__global__ void transpose_wo(const float* __restrict__ in, unsigned short* __restrict__ out) {
    __shared__ float t[32][33];
    int c0 = blockIdx.x * 32, r0 = blockIdx.y * 32;
    t[threadIdx.y][threadIdx.x] = in[(long)(r0 + threadIdx.y) * 1024 + c0 + threadIdx.x];
    __syncthreads();
    out[(long)(c0 + threadIdx.y) * 1024 + r0 + threadIdx.x] = f2bf(t[threadIdx.x][threadIdx.y]);
}

// ---------------- 128x128-tile bf16 MFMA GEMM body ----------------
// C[m][n] = sum_k A[m][k]*Bt[n][k]; A [M][1024], Bt [N][1024] bf16.
// MODE 0: bf16 C[gm*ldc+gn]; MODE 1: bf16 transposed C[gn*ldc+gm] (ushort4); MODE 2: f32
template<int MODE>
__device__ __forceinline__ void gemm128x128(unsigned short* As, unsigned short* Bs,
                                            const unsigned short* __restrict__ A,
                                            const unsigned short* __restrict__ Bt,
                                            void* __restrict__ C, int m0, int n0, int ldc) {
    const int tid = threadIdx.x, wv = tid >> 6, lane = tid & 63, lg = lane >> 4, lr = lane & 15;
    const int wm = wv & 1, wn = wv >> 1;
    f32x4 acc[4][4] = {};
    const unsigned short* Ab = A + (size_t)m0 * D_;
    const unsigned short* Bb = Bt + (size_t)n0 * D_;
    for (int kt = 0; kt < 16; ++kt) {
        __syncthreads();
        #pragma unroll
        for (int it = 0; it < 4; ++it) {
            int c = it * 256 + wv * 64 + lane;
            int row = c >> 3, jj = (c & 7) ^ (row & 7);
            gload16(Ab + (size_t)row * D_ + kt * 64 + jj * 8, &As[(it * 256 + wv * 64) * 8]);
        }
        #pragma unroll
        for (int it = 0; it < 4; ++it) {
            int c = it * 256 + wv * 64 + lane;
            int row = c >> 3, jj = (c & 7) ^ (row & 7);
            gload16(Bb + (size_t)row * D_ + kt * 64 + jj * 8, &Bs[(it * 256 + wv * 64) * 8]);
        }
        __syncthreads();
        #pragma unroll
        for (int kk = 0; kk < 2; ++kk) {
            bf16x8 af[4], bfr[4];
            #pragma unroll
            for (int mf = 0; mf < 4; ++mf) {
                int r = wm * 64 + mf * 16 + lr;
                af[mf] = *(const bf16x8*)&As[(r * 8 + ((kk * 4 + lg) ^ (r & 7))) * 8];
            }
            #pragma unroll
            for (int nf = 0; nf < 4; ++nf) {
                int r = wn * 64 + nf * 16 + lr;
                bfr[nf] = *(const bf16x8*)&Bs[(r * 8 + ((kk * 4 + lg) ^ (r & 7))) * 8];
            }
            #pragma unroll
            for (int mf = 0; mf < 4; ++mf)
                #pragma unroll
                for (int nf = 0; nf < 4; ++nf)
                    acc[mf][nf] = __builtin_amdgcn_mfma_f32_16x16x32_bf16(af[mf], bfr[nf], acc[mf][nf], 0, 0, 0);
        }
    }
    #pragma unroll
    for (int mf = 0; mf < 4; ++mf)
        #pragma unroll
        for (int nf = 0; nf < 4; ++nf) {
            if (MODE == 1) {
                int gm = m0 + wm * 64 + mf * 16 + lg * 4;
                int gn = n0 + wn * 64 + nf * 16 + lr;
                ushort4 pk;
                pk.x = f2bf(acc[mf][nf][0]); pk.y = f2bf(acc[mf][nf][1]);
                pk.z = f2bf(acc[mf][nf][2]); pk.w = f2bf(acc[mf][nf][3]);
                *(ushort4*)&((unsigned short*)C)[(size_t)gn * ldc + gm] = pk;
            } else {
                #pragma unroll
                for (int j = 0; j < 4; ++j) {
                    int gm = m0 + wm * 64 + mf * 16 + lg * 4 + j;
                    int gn = n0 + wn * 64 + nf * 16 + lr;
                    if (MODE == 0) ((unsigned short*)C)[(size_t)gm * ldc + gn] = f2bf(acc[mf][nf][j]);
                    else           ((float*)C)[(size_t)gm * ldc + gn] = acc[mf][nf][j];
                }
            }
        }
}

// ---------------- QKV projection: head-fused wide GEMMs ----------------
// z=0: Q = Eq @ Wq  -> [S][1024];  z=1: K;  z=2: Vt (transposed store [1024][S])
__global__ __launch_bounds__(256, 2) void proj_kernel(
    const unsigned short* __restrict__ Eq, const unsigned short* __restrict__ Ek,
    const unsigned short* __restrict__ Ev, const unsigned short* __restrict__ Wqt,
    const unsigned short* __restrict__ Wkt, const unsigned short* __restrict__ Wvt,
    unsigned short* __restrict__ Qb, unsigned short* __restrict__ Kb,
    unsigned short* __restrict__ Vtb) {
    __shared__ alignas(16) unsigned short As[128 * 64];
    __shared__ alignas(16) unsigned short Bs[128 * 64];
    int m0 = blockIdx.x * 128, n0 = blockIdx.y * 128;
    if (blockIdx.z == 0)      gemm128x128<0>(As, Bs, Eq, Wqt, Qb, m0, n0, 1024);
    else if (blockIdx.z == 1) gemm128x128<0>(As, Bs, Ek, Wkt, Kb, m0, n0, 1024);
    else                      gemm128x128<1>(As, Bs, Ev, Wvt, Vtb, m0, n0, S_);
}

__global__ __launch_bounds__(256, 2) void out_gemm(const unsigned short* __restrict__ Cat,
                                                   const unsigned short* __restrict__ Wot,
                                                   float* __restrict__ Out) {
    __shared__ alignas(16) unsigned short As[128 * 64];
    __shared__ alignas(16) unsigned short Bs[128 * 64];
    gemm128x128<2>(As, Bs, Cat, Wot, Out, blockIdx.x * 128, blockIdx.y * 128, 1024);
}

// ---------------- flash attention, swapped-QK^T, double-buffered ----------------
// grid (S/64, H), 256 thr (4 waves); wave w owns q rows [s0+16w, s0+16w+16); lane's q = lr
__global__ __launch_bounds__(256, 2) void attn_kernel(
    const unsigned short* __restrict__ Qb, const unsigned short* __restrict__ Kb,
    const unsigned short* __restrict__ Vtb, unsigned short* __restrict__ Cat) {
    __shared__ alignas(16) unsigned short Ks[2][64 * 64];
    __shared__ alignas(16) unsigned short Vs[2][64 * 64];

    const int h = blockIdx.y, s0 = blockIdx.x * 64;
    const int tid = threadIdx.x, wv = tid >> 6, lane = tid & 63, lg = lane >> 4, lr = lane & 15;

    const unsigned short* qrow = Qb + (size_t)(s0 + wv * 16 + lr) * D_ + h * 64;
    const bf16x8 qf0 = *(const bf16x8*)(qrow);
    const bf16x8 qf1 = *(const bf16x8*)(qrow + 32);
    // B-frag of Q needs k-elems lg*8..; qf0/qf1 above load lg-dependent slices:
    const bf16x8 q0 = *(const bf16x8*)(qrow + lg * 8);
    const bf16x8 q1 = *(const bf16x8*)(qrow + 32 + lg * 8);
    (void)qf0; (void)qf1;

    float m_run = -1e30f, l_run = 0.f;
    f32x4 o_acc[4] = {};

    const unsigned short* KhB = Kb + h * 64;                 // [S][1024], row stride 1024
    const unsigned short* VhB = Vtb + (size_t)(h * 64) * S_; // [64 dv][S]

    auto stage = [&](int b, int t) {
        #pragma unroll
        for (int it = 0; it < 2; ++it) {
            int c = it * 256 + wv * 64 + lane;
            int row = c >> 3, jj = (c & 7) ^ (row & 7);
            gload16(KhB + (size_t)(t * 64 + row) * D_ + jj * 8, &Ks[b][(it * 256 + wv * 64) * 8]);
        }
        #pragma unroll
        for (int it = 0; it < 2; ++it) {
            int c = it * 256 + wv * 64 + lane;
            int row = c >> 3, jj = (c & 7) ^ (row & 7);
            gload16(VhB + (size_t)row * S_ + t * 64 + jj * 8, &Vs[b][(it * 256 + wv * 64) * 8]);
        }
    };

    stage(0, 0);
    __syncthreads();
    int buf = 0;
    for (int t = 0; t < S_ / 64; ++t) {
        if (t + 1 < S_ / 64) stage(buf ^ 1, t + 1);
        const unsigned short* K_ = Ks[buf];
        const unsigned short* V_ = Vs[buf];

        // S^T tile: sc[n] C-layout: key = n*16 + lg*4 + j, q = lr
        f32x4 sc[4] = {};
        #pragma unroll
        for (int kk = 0; kk < 2; ++kk) {
            bf16x8 q = kk ? q1 : q0;
            #pragma unroll
            for (int n = 0; n < 4; ++n) {
                int r = n * 16 + lr;
                bf16x8 kf = *(const bf16x8*)&K_[(r * 8 + ((kk * 4 + lg) ^ (r & 7))) * 8];
                sc[n] = __builtin_amdgcn_mfma_f32_16x16x32_bf16(kf, q, sc[n], 0, 0, 0);
            }
        }
        float mx = -1e30f;
        #pragma unroll
        for (int n = 0; n < 4; ++n) {
            sc[n] *= 0.125f;
            mx = fmaxf(mx, fmaxf(fmaxf(sc[n][0], sc[n][1]), fmaxf(sc[n][2], sc[n][3])));
        }
        mx = fmaxf(mx, __shfl_xor(mx, 16));
        mx = fmaxf(mx, __shfl_xor(mx, 32));
        float mn = fmaxf(m_run, mx);
        float alpha = __expf(m_run - mn);
        m_run = mn;
        float rs = 0.f;
        #pragma unroll
        for (int n = 0; n < 4; ++n)
            #pragma unroll
            for (int j = 0; j < 4; ++j) {
                float p = __expf(sc[n][j] - mn);
                sc[n][j] = p;
                rs += p;
            }
        rs += __shfl_xor(rs, 16);
        rs += __shfl_xor(rs, 32);
        l_run = l_run * alpha + rs;
        #pragma unroll
        for (int n = 0; n < 4; ++n) o_acc[n] *= alpha;

        // P as PV B-frag, lane-local under k-slot permutation pi(kk,8*lg+i)=32kk+16(i>>2)+4lg+(i&3)
        bf16x8 pB[2];
        #pragma unroll
        for (int kk = 0; kk < 2; ++kk) {
            bf16x8 pb;
            #pragma unroll
            for (int i = 0; i < 4; ++i) pb[i] = (short)f2bf(sc[2 * kk][i]);
            #pragma unroll
            for (int i = 0; i < 4; ++i) pb[4 + i] = (short)f2bf(sc[2 * kk + 1][i]);
            pB[kk] = pb;
        }
        // O^T += V^T(pi) * P^T : A-frag rows dv, k-slots permuted to match pB
        #pragma unroll
        for (int n = 0; n < 4; ++n) {
            int r = n * 16 + lr;
            #pragma unroll
            for (int kk = 0; kk < 2; ++kk) {
                s16x4 lo = *(const s16x4*)&V_[(r * 8 + ((4 * kk + (lg >> 1)) ^ (r & 7))) * 8 + (lg & 1) * 4];
                s16x4 hi = *(const s16x4*)&V_[(r * 8 + ((4 * kk + 2 + (lg >> 1)) ^ (r & 7))) * 8 + (lg & 1) * 4];
                bf16x8 vf;
                vf[0] = lo[0]; vf[1] = lo[1]; vf[2] = lo[2]; vf[3] = lo[3];
                vf[4] = hi[0]; vf[5] = hi[1]; vf[6] = hi[2]; vf[7] = hi[3];
                o_acc[n] = __builtin_amdgcn_mfma_f32_16x16x32_bf16(vf, pB[kk], o_acc[n], 0, 0, 0);
            }
        }
        __syncthreads();
        buf ^= 1;
    }
    float inv_l = 1.f / l_run;
    int s = s0 + wv * 16 + lr;
    #pragma unroll
    for (int n = 0; n < 4; ++n) {
        ushort4 pk;
        pk.x = f2bf(o_acc[n][0] * inv_l);
        pk.y = f2bf(o_acc[n][1] * inv_l);
        pk.z = f2bf(o_acc[n][2] * inv_l);
        pk.w = f2bf(o_acc[n][3] * inv_l);
        *(ushort4*)&Cat[(size_t)s * D_ + h * 64 + n * 16 + lg * 4] = pk;
    }
}

extern "C" void kernel_launch(void* const* d_in, const int* in_sizes, int n_in,
                              void* d_out, int out_size, void* d_ws, size_t ws_size,
                              hipStream_t stream) {
    const float* enc_q = (const float*)d_in[0];
    const float* enc_k = (const float*)d_in[1];
    const float* enc_v = (const float*)d_in[2];
    const float* W_q   = (const float*)d_in[3];
    const float* W_k   = (const float*)d_in[4];
    const float* W_v   = (const float*)d_in[5];
    const float* W_out = (const float*)d_in[6];
    float* out = (float*)d_out;

    unsigned short* Eqb = (unsigned short*)d_ws;       // [S][D] bf16
    unsigned short* Ekb = Eqb + 2048 * 1024;
    unsigned short* Evb = Ekb + 2048 * 1024;
    unsigned short* Wqt = Evb + 2048 * 1024;           // [H*DK][D] bf16
    unsigned short* Wkt = Wqt + 1024 * 1024;
    unsigned short* Wvt = Wkt + 1024 * 1024;
    unsigned short* Wot = Wvt + 1024 * 1024;           // [D][H*DV] transposed bf16
    unsigned short* Qb  = Wot + 1024 * 1024;           // [S][H*DK] bf16
    unsigned short* Kb  = Qb  + 2048 * 1024;           // [S][H*DK]
    unsigned short* Vtb = Kb  + 2048 * 1024;           // [H*DV][S]
    unsigned short* Cat = Vtb + 2048 * 1024;           // [S][H*DV]

    cvt_f32_bf16<<<dim3(2048, 3), 256, 0, stream>>>(enc_q, enc_k, enc_v, Eqb, Ekb, Evb, 524288);
    dim3 tb(32, 32);
    transpose_qkv<<<dim3(2, 32, 48), tb, 0, stream>>>(W_q, W_k, W_v, Wqt, Wkt, Wvt);
    transpose_wo<<<dim3(32, 32), tb, 0, stream>>>(W_out, Wot);
    proj_kernel<<<dim3(16, 8, 3), 256, 0, stream>>>(Eqb, Ekb, Evb, Wqt, Wkt, Wvt, Qb, Kb, Vtb);
    attn_kernel<<<dim3(32, 16), 256, 0, stream>>>(Qb, Kb, Vtb, Cat);
    out_gemm<<<dim3(16, 8), 256, 0, stream>>>(Cat, Wot, out);
}